// Round 1
// baseline (610.633 us; speedup 1.0000x reference)
//
#include <hip/hip_runtime.h>
#include <stdint.h>

#define SEQL 2521
#define LPAD 2560
#define NB 2
#define NH 16
#define HD 128
#define CD 2048
#define KD 2048

typedef float f32x4 __attribute__((ext_vector_type(4)));
typedef __bf16 bf16x8 __attribute__((ext_vector_type(8)));
typedef unsigned short u16x8 __attribute__((ext_vector_type(8)));

static __device__ __forceinline__ unsigned short bf16r(float f){
  union { float f; unsigned u; } v; v.f = f;
  unsigned r = v.u + 0x7FFFu + ((v.u >> 16) & 1u);
  return (unsigned short)(r >> 16);
}
static __device__ __forceinline__ float bf2f(unsigned short s){
  union { unsigned u; float f; } v; v.u = ((unsigned)s) << 16; return v.f;
}
static __device__ __forceinline__ bf16x8 asbf(u16x8 v){ return __builtin_bit_cast(bf16x8, v); }

typedef const __attribute__((address_space(1))) unsigned int* gas1_t;
typedef __attribute__((address_space(3))) unsigned int* las3_t;
static __device__ __forceinline__ void glds16(const void* g, void* l){
  __builtin_amdgcn_global_load_lds((gas1_t)g, (las3_t)l, 16, 0, 0);
}

// ---------------------------------------------------------------- prep
// xb is [NB][LPAD][CD] bf16 (pad rows zero; later reused as attn_out)
__global__ __launch_bounds__(256) void prep_kernel(
    const float* __restrict__ x, const float* __restrict__ wqkv, const float* __restrict__ projw,
    unsigned short* __restrict__ xb, unsigned short* __restrict__ wb, unsigned short* __restrict__ pw)
{
  const int NX = (NB*LPAD*CD)/4;      // 2,621,440
  const int NW = (3*CD*CD)/4;         // 3,145,728
  const int NPj = (CD*CD)/4;          // 1,048,576
  const int total = NX + NW + NPj;
  for (int v = blockIdx.x*256 + threadIdx.x; v < total; v += gridDim.x*256){
    if (v < NX){
      int e = v << 2;
      int row = e >> 11, col = e & 2047;
      int b = (row >= LPAD) ? 1 : 0;
      int l = row - b*LPAD;
      ushort4 o;
      if (l < SEQL){
        const float4 f = *(const float4*)(x + (((long)(b*SEQL + l)) << 11) + col);
        o.x = bf16r(f.x); o.y = bf16r(f.y); o.z = bf16r(f.z); o.w = bf16r(f.w);
      } else { o.x = 0; o.y = 0; o.z = 0; o.w = 0; }
      *(ushort4*)(xb + e) = o;
    } else if (v < NX + NW){
      long i = (long)(v - NX) << 2;
      const float4 f = *(const float4*)(wqkv + i);
      ushort4 o; o.x=bf16r(f.x); o.y=bf16r(f.y); o.z=bf16r(f.z); o.w=bf16r(f.w);
      *(ushort4*)(wb + i) = o;
    } else {
      long i = (long)(v - NX - NW) << 2;
      const float4 f = *(const float4*)(projw + i);
      ushort4 o; o.x=bf16r(f.x); o.y=bf16r(f.y); o.z=bf16r(f.z); o.w=bf16r(f.w);
      *(ushort4*)(pw + i) = o;
    }
  }
}

// ---------------------------------------------------------------- GEMM core
// C[m][n] = sum_k A[m][k]*B[n][k]; A [Mp][KD], B [N][KD] bf16 row-major.
// 128x128 tile, BK=32, 4 waves (2x2 of 64x64), acc[ai][bj] holds
// D[m0+64wm+16ai+4g+r][n0+64wn+16bj+lr]  (verified 16x16x32 C layout).
static __device__ __forceinline__ void gemm_core(
    const unsigned short* __restrict__ A, const unsigned short* __restrict__ Bm,
    unsigned short* As, unsigned short* Bs, int m0, int n0, f32x4 acc[4][4])
{
  const int tid = threadIdx.x;
  const int w = tid >> 6, lane = tid & 63;
  const int g = lane >> 4, lr = lane & 15;
  const int wm = w >> 1, wn = w & 1;
  const unsigned short* aS0 = A + (long)(m0 + (tid >> 2))*KD + ((tid & 3) << 3);
  const unsigned short* aS1 = aS0 + (long)64*KD;
  const unsigned short* bS0 = Bm + (long)(n0 + (tid >> 2))*KD + ((tid & 3) << 3);
  const unsigned short* bS1 = bS0 + (long)64*KD;
  unsigned short* aD0 = As + (w << 9);
  unsigned short* aD1 = As + 2048 + (w << 9);
  unsigned short* bD0 = Bs + (w << 9);
  unsigned short* bD1 = Bs + 2048 + (w << 9);
  const unsigned short* aRd = As + ((wm << 6) + lr)*32 + (g << 3);
  const unsigned short* bRd = Bs + ((wn << 6) + lr)*32 + (g << 3);
  for (int kt = 0; kt < KD/32; ++kt){
    __syncthreads();
    const int ko = kt << 5;
    glds16(aS0 + ko, aD0);
    glds16(aS1 + ko, aD1);
    glds16(bS0 + ko, bD0);
    glds16(bS1 + ko, bD1);
    __syncthreads();
    u16x8 af[4], bfr[4];
#pragma unroll
    for (int i = 0; i < 4; ++i) af[i]  = *(const u16x8*)(aRd + i*16*32);
#pragma unroll
    for (int j = 0; j < 4; ++j) bfr[j] = *(const u16x8*)(bRd + j*16*32);
#pragma unroll
    for (int i = 0; i < 4; ++i)
#pragma unroll
      for (int j = 0; j < 4; ++j)
        acc[i][j] = __builtin_amdgcn_mfma_f32_16x16x32_bf16(asbf(af[i]), asbf(bfr[j]), acc[i][j], 0, 0, 0);
  }
}

// ---------------------------------------------------------------- GEMM1: QKV
// q,k -> [NB*NH][LPAD][HD]; v -> transposed [NB*NH][HD][LPAD]
__global__ __launch_bounds__(256) void gemm_qkv(
    const unsigned short* __restrict__ A, const unsigned short* __restrict__ W,
    const float* __restrict__ qb, const float* __restrict__ vb,
    unsigned short* __restrict__ qg, unsigned short* __restrict__ kg,
    unsigned short* __restrict__ vt)
{
  __shared__ __align__(16) unsigned short As[128*32];
  __shared__ __align__(16) unsigned short Bs[128*32];
  f32x4 acc[4][4] = {};
  const int m0 = blockIdx.x << 7, n0 = blockIdx.y << 7;
  gemm_core(A, W, As, Bs, m0, n0, acc);
  const int tid = threadIdx.x;
  const int w = tid >> 6, lane = tid & 63, g = lane >> 4, lr = lane & 15;
  const int wm = w >> 1, wn = w & 1;
  const int part = n0 >> 11;               // 0=q 1=k 2=v (tiles never straddle)
  const int b = (m0 >= LPAD) ? 1 : 0;
  const int l0 = m0 - b*LPAD;
  const int hb = (n0 & 2047) >> 7;
#pragma unroll
  for (int ai = 0; ai < 4; ++ai){
#pragma unroll
    for (int bj = 0; bj < 4; ++bj){
      const int d = (wn << 6) + (bj << 4) + lr;
      const int mloc = (wm << 6) + (ai << 4) + (g << 2);
      const float bias = (part == 0) ? qb[(hb << 7) + d] : ((part == 2) ? vb[(hb << 7) + d] : 0.f);
      const f32x4 v = acc[ai][bj];
      if (part == 2){
        ushort4 o;
        o.x = bf16r(v[0] + bias); o.y = bf16r(v[1] + bias);
        o.z = bf16r(v[2] + bias); o.w = bf16r(v[3] + bias);
        *(ushort4*)(vt + ((long)((b*NH + hb)*HD + d))*LPAD + l0 + mloc) = o;
      } else {
        unsigned short* dst = (part ? kg : qg) + (((long)(b*NH + hb)*LPAD) + l0 + mloc)*HD + d;
        dst[0]     = bf16r(v[0] + bias);
        dst[HD]    = bf16r(v[1] + bias);
        dst[2*HD]  = bf16r(v[2] + bias);
        dst[3*HD]  = bf16r(v[3] + bias);
      }
    }
  }
}

// ---------------------------------------------------------------- GEMM2: proj
__global__ __launch_bounds__(256) void gemm_proj(
    const unsigned short* __restrict__ A, const unsigned short* __restrict__ W,
    const float* __restrict__ pbias, float* __restrict__ out)
{
  __shared__ __align__(16) unsigned short As[128*32];
  __shared__ __align__(16) unsigned short Bs[128*32];
  f32x4 acc[4][4] = {};
  const int m0 = blockIdx.x << 7, n0 = blockIdx.y << 7;
  gemm_core(A, W, As, Bs, m0, n0, acc);
  const int tid = threadIdx.x;
  const int w = tid >> 6, lane = tid & 63, g = lane >> 4, lr = lane & 15;
  const int wm = w >> 1, wn = w & 1;
  const int b = (m0 >= LPAD) ? 1 : 0;
  const int l0 = m0 - b*LPAD;
#pragma unroll
  for (int ai = 0; ai < 4; ++ai){
#pragma unroll
    for (int bj = 0; bj < 4; ++bj){
      const int n = n0 + (wn << 6) + (bj << 4) + lr;
      const int mloc = (wm << 6) + (ai << 4) + (g << 2);
      const float bias = pbias[n];
      const f32x4 v = acc[ai][bj];
#pragma unroll
      for (int r = 0; r < 4; ++r){
        const int l = l0 + mloc + r;
        if (l < SEQL) out[(((long)b*SEQL + l) << 11) + n] = v[r] + bias;
      }
    }
  }
}

// ---------------------------------------------------------------- rope + norm
__global__ __launch_bounds__(256) void rope_norm(
    unsigned short* __restrict__ qg, unsigned short* __restrict__ kg,
    const float* __restrict__ rope, const float* __restrict__ smlog)
{
  const int w = threadIdx.x >> 6, lane = threadIdx.x & 63;
  const int l = blockIdx.x*4 + w;
  if (l >= SEQL) return;
  const int pb = blockIdx.y;          // part*32 + bh
  const int part = pb >> 5, bh = pb & 31, h = bh & 15;
  unsigned short* base = (part ? kg : qg) + ((long)bh*LPAD + l)*HD + (lane << 1);
  const unsigned u = *(const unsigned*)base;
  const float re = bf2f((unsigned short)(u & 0xffff));
  const float im = bf2f((unsigned short)(u >> 16));
  float ss = re*re + im*im;
#pragma unroll
  for (int o = 1; o < 64; o <<= 1) ss += __shfl_xor(ss, o, 64);
  float inv = 1.f / fmaxf(sqrtf(ss), 1e-12f);
  if (part == 0){
    float sl = smlog[h];
    sl = fminf(sl, 4.605170185988091f);   // log(100)
    inv *= __expf(sl);
  }
  const float cs = rope[l*64 + lane];
  const float sn = rope[SEQL*64 + l*64 + lane];
  const float re2 = (cs*re - sn*im)*inv;
  const float im2 = (sn*re + cs*im)*inv;
  const unsigned o = (unsigned)bf16r(re2) | ((unsigned)bf16r(im2) << 16);
  *(unsigned*)base = o;
}

// ---------------------------------------------------------------- attention
static __device__ __forceinline__ int q_end_of(int q){
  if (q >= SEQL) return 1;
  if (q < 121){
    if (q < 1) return 1;
    if (q < 5) return 5;
    if (q < 21) return 21;
    if (q < 57) return 57;
    return 121;
  }
  if (q < 265) return 265;
  if (q < 521) return 521;
  if (q < 921) return 921;
  if (q < 1497) return 1497;
  return 2521;
}

__global__ __launch_bounds__(256) void attn_kernel(
    const unsigned short* __restrict__ qg, const unsigned short* __restrict__ kg,
    const unsigned short* __restrict__ vt, unsigned short* __restrict__ aout)
{
  __shared__ __align__(16) unsigned short Ks[64*128];   // [kv][hd], 16B-chunk xor-swizzled by kv&7
  __shared__ __align__(16) unsigned short Vs[128*64];   // [d][kv],  16B-chunk xor-swizzled by d&7
  __shared__ __align__(16) unsigned short Ps[4][16*72]; // per-wave P [q16][64+8pad]
  const int tid = threadIdx.x, w = tid >> 6, lane = tid & 63;
  const int g = lane >> 4, lr = lane & 15;
  const int qt = blockIdx.x, bh = blockIdx.y;
  const int q0 = qt << 6, qw = q0 + (w << 4);
  const long kvBase = (long)bh * LPAD * HD;

  u16x8 qf[4];
  {
    const unsigned short* qrow = qg + kvBase + (long)(qw + lr)*HD + (g << 3);
#pragma unroll
    for (int c = 0; c < 4; ++c) qf[c] = *(const u16x8*)(qrow + (c << 5));
  }
  const int qe = q_end_of(qw + lr);
  const int qmax = (q0 + 63 < SEQL - 1) ? q0 + 63 : SEQL - 1;
  const int nt = (q_end_of(qmax) + 63) >> 6;

  float m_run = -1e30f, l_run = 0.f;
  f32x4 acco[8] = {};

  for (int t = 0; t < nt; ++t){
    __syncthreads();
    const int kvb = t << 6;
#pragma unroll
    for (int c = 0; c < 4; ++c){
      const int idx = (c << 8) + tid;
      const int kv = idx >> 4, ch = idx & 15;
      glds16(kg + kvBase + (long)(kvb + kv)*HD + ((ch ^ (kv & 7)) << 3),
             Ks + (c << 11) + (w << 9));
      const int dd = idx >> 3, ch2 = idx & 7;
      glds16(vt + kvBase + (long)dd*LPAD + kvb + ((ch2 ^ (dd & 7)) << 3),
             Vs + (c << 11) + (w << 9));
    }
    __syncthreads();

    // S^T = K * Q^T : lane holds S[q=lr][kv = kvb + 16mf + 4g + r]
    f32x4 accs[4] = {};
#pragma unroll
    for (int mf = 0; mf < 4; ++mf){
      const int kvr = (mf << 4) + lr;
      const unsigned short* krow = Ks + kvr*HD;
      const int sw = kvr & 7;
#pragma unroll
      for (int c = 0; c < 4; ++c){
        u16x8 kf = *(const u16x8*)(krow + ((((c << 2) + g) ^ sw) << 3));
        accs[mf] = __builtin_amdgcn_mfma_f32_16x16x32_bf16(asbf(kf), asbf(qf[c]), accs[mf], 0, 0, 0);
      }
    }

    // mask + online softmax (per lane: q = lr)
    float tmax = -1e30f;
#pragma unroll
    for (int mf = 0; mf < 4; ++mf){
#pragma unroll
      for (int r = 0; r < 4; ++r){
        const int kvg = kvb + (mf << 4) + (g << 2) + r;
        float s = (kvg < qe) ? accs[mf][r] : -1e30f;
        accs[mf][r] = s;
        tmax = fmaxf(tmax, s);
      }
    }
    tmax = fmaxf(tmax, __shfl_xor(tmax, 16, 64));
    tmax = fmaxf(tmax, __shfl_xor(tmax, 32, 64));
    const float mnew = fmaxf(m_run, tmax);
    const float alpha = __expf(m_run - mnew);
    float tsum = 0.f;
#pragma unroll
    for (int mf = 0; mf < 4; ++mf){
#pragma unroll
      for (int r = 0; r < 4; ++r){
        const float p = __expf(accs[mf][r] - mnew);
        accs[mf][r] = p;
        tsum += p;
      }
    }
    tsum += __shfl_xor(tsum, 16, 64);
    tsum += __shfl_xor(tsum, 32, 64);
    l_run = l_run*alpha + tsum;
    m_run = mnew;

    // O-rows live at q = 4g + r : broadcast alpha
    const float a0 = __shfl(alpha, (g << 2) + 0, 64);
    const float a1 = __shfl(alpha, (g << 2) + 1, 64);
    const float a2 = __shfl(alpha, (g << 2) + 2, 64);
    const float a3 = __shfl(alpha, (g << 2) + 3, 64);
#pragma unroll
    for (int nf = 0; nf < 8; ++nf){
      acco[nf][0] *= a0; acco[nf][1] *= a1; acco[nf][2] *= a2; acco[nf][3] *= a3;
    }

    // pack P -> LDS [q=lr][kv], 4 consecutive kv per write
    unsigned short* prow = &Ps[w][lr*72 + (g << 2)];
#pragma unroll
    for (int mf = 0; mf < 4; ++mf){
      uint2 pk;
      pk.x = (unsigned)bf16r(accs[mf][0]) | ((unsigned)bf16r(accs[mf][1]) << 16);
      pk.y = (unsigned)bf16r(accs[mf][2]) | ((unsigned)bf16r(accs[mf][3]) << 16);
      *(uint2*)(prow + (mf << 4)) = pk;
    }

    // O += P * V
#pragma unroll
    for (int c = 0; c < 2; ++c){
      u16x8 pf = *(const u16x8*)(&Ps[w][lr*72 + (c << 5) + (g << 3)]);
      const int sw2 = lr & 7;
#pragma unroll
      for (int nf = 0; nf < 8; ++nf){
        u16x8 vf = *(const u16x8*)(Vs + ((nf << 4) + lr)*64 + ((((c << 2) + g) ^ sw2) << 3));
        acco[nf] = __builtin_amdgcn_mfma_f32_16x16x32_bf16(asbf(pf), asbf(vf), acco[nf], 0, 0, 0);
      }
    }
  }

  const float rcp = 1.f / l_run;
  const float li0 = __shfl(rcp, (g << 2) + 0, 64);
  const float li1 = __shfl(rcp, (g << 2) + 1, 64);
  const float li2 = __shfl(rcp, (g << 2) + 2, 64);
  const float li3 = __shfl(rcp, (g << 2) + 3, 64);
  const int b = bh >> 4, h = bh & 15;
#pragma unroll
  for (int r = 0; r < 4; ++r){
    const int qq = qw + (g << 2) + r;
    if (qq < SEQL){
      const float lir = (r == 0) ? li0 : ((r == 1) ? li1 : ((r == 2) ? li2 : li3));
      unsigned short* dst = aout + (((long)(b*LPAD + qq)) << 11) + (h << 7) + lr;
#pragma unroll
      for (int nf = 0; nf < 8; ++nf)
        dst[nf << 4] = bf16r(acco[nf][r] * lir);
    }
  }
}

// ---------------------------------------------------------------- launch
extern "C" void kernel_launch(void* const* d_in, const int* in_sizes, int n_in,
                              void* d_out, int out_size, void* d_ws, size_t ws_size,
                              hipStream_t stream) {
  const float* x     = (const float*)d_in[0];
  const float* wqkv  = (const float*)d_in[1];
  const float* qb    = (const float*)d_in[2];
  const float* vb    = (const float*)d_in[3];
  const float* smlog = (const float*)d_in[4];
  const float* projw = (const float*)d_in[5];
  const float* projb = (const float*)d_in[6];
  const float* rope  = (const float*)d_in[7];
  // d_in[8] attn_bias: computed analytically, never read
  float* out = (float*)d_out;

  unsigned short* xb = (unsigned short*)d_ws;        // [NB][LPAD][CD]; reused as attn_out
  unsigned short* wb = xb + (size_t)NB*LPAD*CD;      // 10,485,760
  unsigned short* pw = wb + (size_t)3*CD*CD;         // +12,582,912
  unsigned short* qg = pw + (size_t)CD*CD;           // +4,194,304
  unsigned short* kg = qg + (size_t)NB*NH*LPAD*HD;   // +10,485,760
  unsigned short* vt = kg + (size_t)NB*NH*LPAD*HD;   // +10,485,760 (total 117,440,512 B)

  prep_kernel<<<2048, 256, 0, stream>>>(x, wqkv, projw, xb, wb, pw);
  gemm_qkv<<<dim3(40, 48), 256, 0, stream>>>(xb, wb, qb, vb, qg, kg, vt);
  rope_norm<<<dim3(631, 64), 256, 0, stream>>>(qg, kg, rope, smlog);
  attn_kernel<<<dim3(40, 32), 256, 0, stream>>>(qg, kg, vt, xb);
  gemm_proj<<<dim3(40, 16), 256, 0, stream>>>(xb, pw, projb, out);
}

// Round 2
// 574.212 us; speedup vs baseline: 1.0634x; 1.0634x over previous
//
#include <hip/hip_runtime.h>
#include <stdint.h>

#define SEQL 2521
#define LPAD 2560
#define NB 2
#define NH 16
#define HD 128
#define CD 2048
#define KD 2048

typedef float f32x4 __attribute__((ext_vector_type(4)));
typedef __bf16 bf16x8 __attribute__((ext_vector_type(8)));
typedef unsigned short u16x8 __attribute__((ext_vector_type(8)));

static __device__ __forceinline__ unsigned short bf16c(float f){
  __bf16 h = (__bf16)f;
  return __builtin_bit_cast(unsigned short, h);
}
static __device__ __forceinline__ float bf2f(unsigned short s){
  union { unsigned u; float f; } v; v.u = ((unsigned)s) << 16; return v.f;
}
static __device__ __forceinline__ bf16x8 asbf(u16x8 v){ return __builtin_bit_cast(bf16x8, v); }

typedef const __attribute__((address_space(1))) unsigned int* gas1_t;
typedef __attribute__((address_space(3))) unsigned int* las3_t;
static __device__ __forceinline__ void glds16(const void* g, void* l){
  __builtin_amdgcn_global_load_lds((gas1_t)g, (las3_t)l, 16, 0, 0);
}

// ---------------------------------------------------------------- prep
// xb is [NB][LPAD][CD] bf16 (pad rows zero; later reused as attn_out)
__global__ __launch_bounds__(256) void prep_kernel(
    const float* __restrict__ x, const float* __restrict__ wqkv, const float* __restrict__ projw,
    unsigned short* __restrict__ xb, unsigned short* __restrict__ wb, unsigned short* __restrict__ pw)
{
  const int NX = (NB*LPAD*CD)/4;      // 2,621,440
  const int NW = (3*CD*CD)/4;         // 3,145,728
  const int NPj = (CD*CD)/4;          // 1,048,576
  const int total = NX + NW + NPj;
  for (int v = blockIdx.x*256 + threadIdx.x; v < total; v += gridDim.x*256){
    if (v < NX){
      int e = v << 2;
      int row = e >> 11, col = e & 2047;
      int b = (row >= LPAD) ? 1 : 0;
      int l = row - b*LPAD;
      ushort4 o;
      if (l < SEQL){
        const float4 f = *(const float4*)(x + (((long)(b*SEQL + l)) << 11) + col);
        o.x = bf16c(f.x); o.y = bf16c(f.y); o.z = bf16c(f.z); o.w = bf16c(f.w);
      } else { o.x = 0; o.y = 0; o.z = 0; o.w = 0; }
      *(ushort4*)(xb + e) = o;
    } else if (v < NX + NW){
      long i = (long)(v - NX) << 2;
      const float4 f = *(const float4*)(wqkv + i);
      ushort4 o; o.x=bf16c(f.x); o.y=bf16c(f.y); o.z=bf16c(f.z); o.w=bf16c(f.w);
      *(ushort4*)(wb + i) = o;
    } else {
      long i = (long)(v - NX - NW) << 2;
      const float4 f = *(const float4*)(projw + i);
      ushort4 o; o.x=bf16c(f.x); o.y=bf16c(f.y); o.z=bf16c(f.z); o.w=bf16c(f.w);
      *(ushort4*)(pw + i) = o;
    }
  }
}

// ---------------------------------------------------------------- GEMM core
static __device__ __forceinline__ void gemm_core(
    const unsigned short* __restrict__ A, const unsigned short* __restrict__ Bm,
    unsigned short* As, unsigned short* Bs, int m0, int n0, f32x4 acc[4][4])
{
  const int tid = threadIdx.x;
  const int w = tid >> 6, lane = tid & 63;
  const int g = lane >> 4, lr = lane & 15;
  const int wm = w >> 1, wn = w & 1;
  const unsigned short* aS0 = A + (long)(m0 + (tid >> 2))*KD + ((tid & 3) << 3);
  const unsigned short* aS1 = aS0 + (long)64*KD;
  const unsigned short* bS0 = Bm + (long)(n0 + (tid >> 2))*KD + ((tid & 3) << 3);
  const unsigned short* bS1 = bS0 + (long)64*KD;
  unsigned short* aD0 = As + (w << 9);
  unsigned short* aD1 = As + 2048 + (w << 9);
  unsigned short* bD0 = Bs + (w << 9);
  unsigned short* bD1 = Bs + 2048 + (w << 9);
  const unsigned short* aRd = As + ((wm << 6) + lr)*32 + (g << 3);
  const unsigned short* bRd = Bs + ((wn << 6) + lr)*32 + (g << 3);
  for (int kt = 0; kt < KD/32; ++kt){
    __syncthreads();
    const int ko = kt << 5;
    glds16(aS0 + ko, aD0);
    glds16(aS1 + ko, aD1);
    glds16(bS0 + ko, bD0);
    glds16(bS1 + ko, bD1);
    __syncthreads();
    u16x8 af[4], bfr[4];
#pragma unroll
    for (int i = 0; i < 4; ++i) af[i]  = *(const u16x8*)(aRd + i*16*32);
#pragma unroll
    for (int j = 0; j < 4; ++j) bfr[j] = *(const u16x8*)(bRd + j*16*32);
#pragma unroll
    for (int i = 0; i < 4; ++i)
#pragma unroll
      for (int j = 0; j < 4; ++j)
        acc[i][j] = __builtin_amdgcn_mfma_f32_16x16x32_bf16(asbf(af[i]), asbf(bfr[j]), acc[i][j], 0, 0, 0);
  }
}

// ---------------------------------------------------------------- GEMM1: QKV
__global__ __launch_bounds__(256) void gemm_qkv(
    const unsigned short* __restrict__ A, const unsigned short* __restrict__ W,
    const float* __restrict__ qb, const float* __restrict__ vb,
    unsigned short* __restrict__ qg, unsigned short* __restrict__ kg,
    unsigned short* __restrict__ vt)
{
  __shared__ __align__(16) unsigned short As[128*32];
  __shared__ __align__(16) unsigned short Bs[128*32];
  f32x4 acc[4][4] = {};
  const int m0 = blockIdx.x << 7, n0 = blockIdx.y << 7;
  gemm_core(A, W, As, Bs, m0, n0, acc);
  const int tid = threadIdx.x;
  const int w = tid >> 6, lane = tid & 63, g = lane >> 4, lr = lane & 15;
  const int wm = w >> 1, wn = w & 1;
  const int part = n0 >> 11;               // 0=q 1=k 2=v
  const int b = (m0 >= LPAD) ? 1 : 0;
  const int l0 = m0 - b*LPAD;
  const int hb = (n0 & 2047) >> 7;
#pragma unroll
  for (int ai = 0; ai < 4; ++ai){
#pragma unroll
    for (int bj = 0; bj < 4; ++bj){
      const int d = (wn << 6) + (bj << 4) + lr;
      const int mloc = (wm << 6) + (ai << 4) + (g << 2);
      const float bias = (part == 0) ? qb[(hb << 7) + d] : ((part == 2) ? vb[(hb << 7) + d] : 0.f);
      const f32x4 v = acc[ai][bj];
      if (part == 2){
        ushort4 o;
        o.x = bf16c(v[0] + bias); o.y = bf16c(v[1] + bias);
        o.z = bf16c(v[2] + bias); o.w = bf16c(v[3] + bias);
        *(ushort4*)(vt + ((long)((b*NH + hb)*HD + d))*LPAD + l0 + mloc) = o;
      } else {
        unsigned short* dst = (part ? kg : qg) + (((long)(b*NH + hb)*LPAD) + l0 + mloc)*HD + d;
        dst[0]     = bf16c(v[0] + bias);
        dst[HD]    = bf16c(v[1] + bias);
        dst[2*HD]  = bf16c(v[2] + bias);
        dst[3*HD]  = bf16c(v[3] + bias);
      }
    }
  }
}

// ---------------------------------------------------------------- GEMM2: proj
__global__ __launch_bounds__(256) void gemm_proj(
    const unsigned short* __restrict__ A, const unsigned short* __restrict__ W,
    const float* __restrict__ pbias, float* __restrict__ out)
{
  __shared__ __align__(16) unsigned short As[128*32];
  __shared__ __align__(16) unsigned short Bs[128*32];
  f32x4 acc[4][4] = {};
  const int m0 = blockIdx.x << 7, n0 = blockIdx.y << 7;
  gemm_core(A, W, As, Bs, m0, n0, acc);
  const int tid = threadIdx.x;
  const int w = tid >> 6, lane = tid & 63, g = lane >> 4, lr = lane & 15;
  const int wm = w >> 1, wn = w & 1;
  const int b = (m0 >= LPAD) ? 1 : 0;
  const int l0 = m0 - b*LPAD;
#pragma unroll
  for (int ai = 0; ai < 4; ++ai){
#pragma unroll
    for (int bj = 0; bj < 4; ++bj){
      const int n = n0 + (wn << 6) + (bj << 4) + lr;
      const int mloc = (wm << 6) + (ai << 4) + (g << 2);
      const float bias = pbias[n];
      const f32x4 v = acc[ai][bj];
#pragma unroll
      for (int r = 0; r < 4; ++r){
        const int l = l0 + mloc + r;
        if (l < SEQL) out[(((long)b*SEQL + l) << 11) + n] = v[r] + bias;
      }
    }
  }
}

// ---------------------------------------------------------------- rope + norm
// 16 lanes per row; q additionally scaled by exp(min(sl,log100)) * log2(e)
// (log2e fold lets attention softmax use exp2 directly).
__global__ __launch_bounds__(256) void rope_norm(
    unsigned short* __restrict__ qg, unsigned short* __restrict__ kg,
    const float* __restrict__ rope, const float* __restrict__ smlog)
{
  const int sub = threadIdx.x & 15;
  const int l = blockIdx.x*16 + (threadIdx.x >> 4);
  if (l >= SEQL) return;
  const int pb = blockIdx.y;          // part*32 + bh
  const int part = pb >> 5, bh = pb & 31, h = bh & 15;
  unsigned short* base = (part ? kg : qg) + ((long)bh*LPAD + l)*HD + (sub << 3);
  const u16x8 v = *(const u16x8*)base;
  float f[8];
#pragma unroll
  for (int i = 0; i < 8; ++i) f[i] = bf2f(v[i]);
  float ss = 0.f;
#pragma unroll
  for (int i = 0; i < 8; ++i) ss += f[i]*f[i];
  ss += __shfl_xor(ss, 1, 16);
  ss += __shfl_xor(ss, 2, 16);
  ss += __shfl_xor(ss, 4, 16);
  ss += __shfl_xor(ss, 8, 16);
  float inv = 1.f / fmaxf(sqrtf(ss), 1e-12f);
  if (part == 0){
    float sl = fminf(smlog[h], 4.605170185988091f);   // log(100)
    inv *= __expf(sl) * 1.4426950408889634f;          // fold log2(e)
  }
  const float4 cs = *(const float4*)(rope + (long)l*64 + (sub << 2));
  const float4 sn = *(const float4*)(rope + (long)(SEQL + l)*64 + (sub << 2));
  u16x8 o;
  const float c4[4] = {cs.x, cs.y, cs.z, cs.w};
  const float s4[4] = {sn.x, sn.y, sn.z, sn.w};
#pragma unroll
  for (int p = 0; p < 4; ++p){
    const float re = f[2*p], im = f[2*p+1];
    o[2*p]   = bf16c((c4[p]*re - s4[p]*im)*inv);
    o[2*p+1] = bf16c((s4[p]*re + c4[p]*im)*inv);
  }
  *(u16x8*)base = o;
}

// ---------------------------------------------------------------- attention
static __device__ __forceinline__ int q_end_of(int q){
  if (q >= SEQL) return 1;
  if (q < 121){
    if (q < 1) return 1;
    if (q < 5) return 5;
    if (q < 21) return 21;
    if (q < 57) return 57;
    return 121;
  }
  if (q < 265) return 265;
  if (q < 521) return 521;
  if (q < 921) return 921;
  if (q < 1497) return 1497;
  return 2521;
}

// 8 waves x 16 q-rows = 128 q-rows per block; KV tile 64.
__global__ __launch_bounds__(512) void attn_kernel(
    const unsigned short* __restrict__ qg, const unsigned short* __restrict__ kg,
    const unsigned short* __restrict__ vt, unsigned short* __restrict__ aout)
{
  __shared__ __align__(16) unsigned short Ks[64*128];   // [kv][hd], 16B-chunk xor-swizzled by kv&7
  __shared__ __align__(16) unsigned short Vs[128*64];   // [d][kv],  16B-chunk xor-swizzled by d&7
  __shared__ __align__(16) unsigned short Ps[8][16*72]; // per-wave P [q16][64+8pad]
  const int tid = threadIdx.x, w = tid >> 6, lane = tid & 63;
  const int g = lane >> 4, lr = lane & 15;
  const int qt = (int)gridDim.x - 1 - (int)blockIdx.x;  // longest blocks first
  const int bh = blockIdx.y;
  const int q0 = qt << 7, qw = q0 + (w << 4);
  const long kvBase = (long)bh * LPAD * HD;

  u16x8 qf[4];
  {
    const unsigned short* qrow = qg + kvBase + (long)(qw + lr)*HD + (g << 3);
#pragma unroll
    for (int c = 0; c < 4; ++c) qf[c] = *(const u16x8*)(qrow + (c << 5));
  }
  const int qe  = q_end_of(qw + lr);
  const int qe0 = q_end_of(qw);                       // min over wave's lanes
  const int qmax = (q0 + 127 < SEQL - 1) ? q0 + 127 : SEQL - 1;
  const int nt = (q_end_of(qmax) + 63) >> 6;

  float m2 = -1e30f, l_run = 0.f;                     // log2-domain running max
  f32x4 acco[8] = {};

  for (int t = 0; t < nt; ++t){
    __syncthreads();
    const int kvb = t << 6;
#pragma unroll
    for (int c = 0; c < 2; ++c){
      const int idx = (c << 9) + tid;                 // 0..1023
      const int kv = idx >> 4, ch = idx & 15;
      glds16(kg + kvBase + (long)(kvb + kv)*HD + ((ch ^ (kv & 7)) << 3),
             Ks + (c << 12) + (w << 9));
      const int dd = idx >> 3, ch2 = idx & 7;
      glds16(vt + kvBase + (long)dd*LPAD + kvb + ((ch2 ^ (dd & 7)) << 3),
             Vs + (c << 12) + (w << 9));
    }
    __syncthreads();

    // S^T = K * Q^T : lane holds S[q=lr][kv = kvb + 16mf + 4g + r] (log2-scaled)
    f32x4 accs[4] = {};
    __builtin_amdgcn_s_setprio(1);
#pragma unroll
    for (int mf = 0; mf < 4; ++mf){
      const int kvr = (mf << 4) + lr;
      const unsigned short* krow = Ks + kvr*HD;
      const int sw = kvr & 7;
#pragma unroll
      for (int c = 0; c < 4; ++c){
        u16x8 kf = *(const u16x8*)(krow + ((((c << 2) + g) ^ sw) << 3));
        accs[mf] = __builtin_amdgcn_mfma_f32_16x16x32_bf16(asbf(kf), asbf(qf[c]), accs[mf], 0, 0, 0);
      }
    }
    __builtin_amdgcn_s_setprio(0);

    // mask (skip if tile fully visible for this wave) + row max
    float tmax = -1e30f;
    if (kvb + 64 <= qe0){
#pragma unroll
      for (int mf = 0; mf < 4; ++mf)
#pragma unroll
        for (int r = 0; r < 4; ++r) tmax = fmaxf(tmax, accs[mf][r]);
    } else {
#pragma unroll
      for (int mf = 0; mf < 4; ++mf){
#pragma unroll
        for (int r = 0; r < 4; ++r){
          const int kvg = kvb + (mf << 4) + (g << 2) + r;
          float s = (kvg < qe) ? accs[mf][r] : -1e30f;
          accs[mf][r] = s;
          tmax = fmaxf(tmax, s);
        }
      }
    }
    tmax = fmaxf(tmax, __shfl_xor(tmax, 16, 64));
    tmax = fmaxf(tmax, __shfl_xor(tmax, 32, 64));

    // T13 defer-max: only rescale when some row grew past threshold (2^11)
    float alpha = 1.f;
    const bool need = !__all(tmax <= m2 + 11.0f);
    if (need){
      const float mnew = fmaxf(m2, tmax);
      alpha = exp2f(m2 - mnew);
      m2 = mnew;
      const float a0 = __shfl(alpha, (g << 2) + 0, 64);
      const float a1 = __shfl(alpha, (g << 2) + 1, 64);
      const float a2 = __shfl(alpha, (g << 2) + 2, 64);
      const float a3 = __shfl(alpha, (g << 2) + 3, 64);
#pragma unroll
      for (int nf = 0; nf < 8; ++nf){
        acco[nf][0] *= a0; acco[nf][1] *= a1; acco[nf][2] *= a2; acco[nf][3] *= a3;
      }
    }

    float tsum = 0.f;
#pragma unroll
    for (int mf = 0; mf < 4; ++mf){
#pragma unroll
      for (int r = 0; r < 4; ++r){
        const float p = exp2f(accs[mf][r] - m2);
        accs[mf][r] = p;
        tsum += p;
      }
    }
    tsum += __shfl_xor(tsum, 16, 64);
    tsum += __shfl_xor(tsum, 32, 64);
    l_run = l_run*alpha + tsum;

    // pack P -> LDS [q=lr][kv]
    unsigned short* prow = &Ps[w][lr*72 + (g << 2)];
#pragma unroll
    for (int mf = 0; mf < 4; ++mf){
      uint2 pk;
      pk.x = (unsigned)bf16c(accs[mf][0]) | ((unsigned)bf16c(accs[mf][1]) << 16);
      pk.y = (unsigned)bf16c(accs[mf][2]) | ((unsigned)bf16c(accs[mf][3]) << 16);
      *(uint2*)(prow + (mf << 4)) = pk;
    }

    // O += P * V
    __builtin_amdgcn_s_setprio(1);
#pragma unroll
    for (int c = 0; c < 2; ++c){
      u16x8 pf = *(const u16x8*)(&Ps[w][lr*72 + (c << 5) + (g << 3)]);
      const int sw2 = lr & 7;
#pragma unroll
      for (int nf = 0; nf < 8; ++nf){
        u16x8 vf = *(const u16x8*)(Vs + ((nf << 4) + lr)*64 + ((((c << 2) + g) ^ sw2) << 3));
        acco[nf] = __builtin_amdgcn_mfma_f32_16x16x32_bf16(asbf(pf), asbf(vf), acco[nf], 0, 0, 0);
      }
    }
    __builtin_amdgcn_s_setprio(0);
  }

  const float rcp = 1.f / l_run;
  const float li0 = __shfl(rcp, (g << 2) + 0, 64);
  const float li1 = __shfl(rcp, (g << 2) + 1, 64);
  const float li2 = __shfl(rcp, (g << 2) + 2, 64);
  const float li3 = __shfl(rcp, (g << 2) + 3, 64);
  const int b = bh >> 4, h = bh & 15;
#pragma unroll
  for (int r = 0; r < 4; ++r){
    const int qq = qw + (g << 2) + r;
    if (qq < SEQL){
      const float lir = (r == 0) ? li0 : ((r == 1) ? li1 : ((r == 2) ? li2 : li3));
      unsigned short* dst = aout + (((long)(b*LPAD + qq)) << 11) + (h << 7) + lr;
#pragma unroll
      for (int nf = 0; nf < 8; ++nf)
        dst[nf << 4] = bf16c(acco[nf][r] * lir);
    }
  }
}

// ---------------------------------------------------------------- launch
extern "C" void kernel_launch(void* const* d_in, const int* in_sizes, int n_in,
                              void* d_out, int out_size, void* d_ws, size_t ws_size,
                              hipStream_t stream) {
  const float* x     = (const float*)d_in[0];
  const float* wqkv  = (const float*)d_in[1];
  const float* qb    = (const float*)d_in[2];
  const float* vb    = (const float*)d_in[3];
  const float* smlog = (const float*)d_in[4];
  const float* projw = (const float*)d_in[5];
  const float* projb = (const float*)d_in[6];
  const float* rope  = (const float*)d_in[7];
  // d_in[8] attn_bias: computed analytically, never read
  float* out = (float*)d_out;

  unsigned short* xb = (unsigned short*)d_ws;        // [NB][LPAD][CD]; reused as attn_out
  unsigned short* wb = xb + (size_t)NB*LPAD*CD;
  unsigned short* pw = wb + (size_t)3*CD*CD;
  unsigned short* qg = pw + (size_t)CD*CD;
  unsigned short* kg = qg + (size_t)NB*NH*LPAD*HD;
  unsigned short* vt = kg + (size_t)NB*NH*LPAD*HD;

  prep_kernel<<<2048, 256, 0, stream>>>(x, wqkv, projw, xb, wb, pw);
  gemm_qkv<<<dim3(40, 48), 256, 0, stream>>>(xb, wb, qb, vb, qg, kg, vt);
  rope_norm<<<dim3(158, 64), 256, 0, stream>>>(qg, kg, rope, smlog);
  attn_kernel<<<dim3(20, 32), 512, 0, stream>>>(qg, kg, vt, xb);
  gemm_proj<<<dim3(40, 16), 256, 0, stream>>>(xb, pw, projb, out);
}

// Round 3
// 535.273 us; speedup vs baseline: 1.1408x; 1.0727x over previous
//
#include <hip/hip_runtime.h>
#include <stdint.h>

#define SEQL 2521
#define LPAD 2560
#define NB 2
#define NH 16
#define HD 128
#define CD 2048
#define KD 2048

typedef float f32x4 __attribute__((ext_vector_type(4)));
typedef __bf16 bf16x8 __attribute__((ext_vector_type(8)));
typedef unsigned short u16x8 __attribute__((ext_vector_type(8)));

static __device__ __forceinline__ unsigned short bf16c(float f){
  __bf16 h = (__bf16)f;
  return __builtin_bit_cast(unsigned short, h);
}
static __device__ __forceinline__ float bf2f(unsigned short s){
  union { unsigned u; float f; } v; v.u = ((unsigned)s) << 16; return v.f;
}
static __device__ __forceinline__ bf16x8 asbf(u16x8 v){ return __builtin_bit_cast(bf16x8, v); }

typedef const __attribute__((address_space(1))) unsigned int* gas1_t;
typedef __attribute__((address_space(3))) unsigned int* las3_t;
static __device__ __forceinline__ void glds16(const void* g, void* l){
  __builtin_amdgcn_global_load_lds((gas1_t)g, (las3_t)l, 16, 0, 0);
}

// ---------------------------------------------------------------- prep
__global__ __launch_bounds__(256) void prep_kernel(
    const float* __restrict__ x, const float* __restrict__ wqkv, const float* __restrict__ projw,
    unsigned short* __restrict__ xb, unsigned short* __restrict__ wb, unsigned short* __restrict__ pw)
{
  const int NX = (NB*LPAD*CD)/4;
  const int NW = (3*CD*CD)/4;
  const int NPj = (CD*CD)/4;
  const int total = NX + NW + NPj;
  for (int v = blockIdx.x*256 + threadIdx.x; v < total; v += gridDim.x*256){
    if (v < NX){
      int e = v << 2;
      int row = e >> 11, col = e & 2047;
      int b = (row >= LPAD) ? 1 : 0;
      int l = row - b*LPAD;
      ushort4 o;
      if (l < SEQL){
        const float4 f = *(const float4*)(x + (((long)(b*SEQL + l)) << 11) + col);
        o.x = bf16c(f.x); o.y = bf16c(f.y); o.z = bf16c(f.z); o.w = bf16c(f.w);
      } else { o.x = 0; o.y = 0; o.z = 0; o.w = 0; }
      *(ushort4*)(xb + e) = o;
    } else if (v < NX + NW){
      long i = (long)(v - NX) << 2;
      const float4 f = *(const float4*)(wqkv + i);
      ushort4 o; o.x=bf16c(f.x); o.y=bf16c(f.y); o.z=bf16c(f.z); o.w=bf16c(f.w);
      *(ushort4*)(wb + i) = o;
    } else {
      long i = (long)(v - NX - NW) << 2;
      const float4 f = *(const float4*)(projw + i);
      ushort4 o; o.x=bf16c(f.x); o.y=bf16c(f.y); o.z=bf16c(f.z); o.w=bf16c(f.w);
      *(ushort4*)(pw + i) = o;
    }
  }
}

// ---------------------------------------------------------------- 8-phase 256x256 GEMM core
// C[m][n] = sum_k A[m][k]*B[n][k]; 8 waves (2M x 4N); per-wave 128x64 out.
// LDS 128 KiB: buf{0,1} x (A 256x64 | B 256x64) bf16, XOR-swizzled:
//   colelem ^= (row&7)<<3  (16B-chunk swizzle; stage source pre-swizzled).
// Phase schedule per K-tile pair (2it even->buf0, odd->buf1):
//  ph0: rd B(all)+A(i01) buf0 ; stage buf1.A.lo<-Kt[2it+1] ; mfma q0
//  ph1: rd A(i23)             ; stage buf1.A.hi<-Kt[2it+1] ; mfma q1
//  ph2: rd A(i45)             ; stage buf0.B.lo<-Kt[2it+2] ; mfma q2
//  ph3: rd A(i67)             ; stage buf0.B.hi<-Kt[2it+2] ; mfma q3 ; vmcnt(4); bar
//  ph4-7: same on buf1, staging buf0.A.lo/hi<-Kt[2it+2], buf1.B.lo/hi<-Kt[2it+3]
//  vmcnt(4) at ph3/ph7 end forces all loads except the newest 2 half-tiles.
static __device__ __forceinline__ void gemm8p(
    const unsigned short* __restrict__ A, const unsigned short* __restrict__ Bm,
    unsigned short* lds, int m0, int n0, f32x4 acc[8][4])
{
  const int tid = threadIdx.x;
  const int w = tid >> 6, lane = tid & 63;
  const int g = lane >> 4, lr = lane & 15;
  const int wm = w >> 2, wn = w & 3;
  const int xorv = (lr & 7) << 3;             // elem
  const int off0 = (g << 3) ^ xorv;           // ks=0 col-elem (ks=1: ^32)
  const int arow = wm*128 + lr;
  const int brow = wn*64 + lr;

  auto stage = [&](int mat, int kt, int half, int buf){
    const unsigned short* G = mat ? Bm : A;
    const int base0 = mat ? n0 : m0;
    unsigned short* lb = lds + buf*32768 + mat*16384;
#pragma unroll
    for (int p = 0; p < 2; ++p){
      const int cb_ = (half<<10) + (p<<9) + (w<<6);
      const int c = cb_ + lane;
      const int row = c >> 3, cc = c & 7;
      glds16(G + (size_t)(base0 + row)*KD + (kt<<6) + ((cc ^ (row & 7)) << 3),
             lb + (cb_ << 3));
    }
  };
  auto rdA = [&](int buf, int i, int ks)->u16x8 {
    return *(const u16x8*)(lds + buf*32768 + (arow + i*16)*64 + (off0 ^ (ks<<5)));
  };
  auto rdB = [&](int buf, int j, int ks)->u16x8 {
    return *(const u16x8*)(lds + buf*32768 + 16384 + (brow + j*16)*64 + (off0 ^ (ks<<5)));
  };

  u16x8 bfr[4][2], af[2][2];
  auto mfma16 = [&](int q){
#pragma unroll
    for (int i2 = 0; i2 < 2; ++i2)
#pragma unroll
      for (int ks = 0; ks < 2; ++ks)
#pragma unroll
        for (int j = 0; j < 4; ++j)
          acc[2*q+i2][j] = __builtin_amdgcn_mfma_f32_16x16x32_bf16(
              asbf(af[i2][ks]), asbf(bfr[j][ks]), acc[2*q+i2][j], 0, 0, 0);
  };

#define PH_SYNC_MFMA(Q) \
    __builtin_amdgcn_s_barrier(); \
    asm volatile("s_waitcnt lgkmcnt(0)" ::: "memory"); \
    __builtin_amdgcn_s_setprio(1); mfma16(Q); __builtin_amdgcn_s_setprio(0);

  // prologue: Kt0 full -> buf0 ; Kt1.B -> buf1
  stage(0, 0, 0, 0); stage(0, 0, 1, 0);
  stage(1, 0, 0, 0); stage(1, 0, 1, 0);
  stage(1, 1, 0, 1); stage(1, 1, 1, 1);
  asm volatile("s_waitcnt vmcnt(4)" ::: "memory");
  __builtin_amdgcn_s_barrier();

  const int NI = KD >> 7;                     // 16 pairs
  for (int it = 0; it < NI; ++it){
    const int kt = it << 1;
    const bool last = (it == NI-1);
    // ---- even tile (buf0) ----
#pragma unroll
    for (int j = 0; j < 4; ++j){ bfr[j][0]=rdB(0,j,0); bfr[j][1]=rdB(0,j,1); }
    af[0][0]=rdA(0,0,0); af[0][1]=rdA(0,0,1); af[1][0]=rdA(0,1,0); af[1][1]=rdA(0,1,1);
    stage(0, kt+1, 0, 1);
    PH_SYNC_MFMA(0)
    __builtin_amdgcn_s_barrier();

    af[0][0]=rdA(0,2,0); af[0][1]=rdA(0,2,1); af[1][0]=rdA(0,3,0); af[1][1]=rdA(0,3,1);
    stage(0, kt+1, 1, 1);
    PH_SYNC_MFMA(1)
    __builtin_amdgcn_s_barrier();

    af[0][0]=rdA(0,4,0); af[0][1]=rdA(0,4,1); af[1][0]=rdA(0,5,0); af[1][1]=rdA(0,5,1);
    if (!last) stage(1, kt+2, 0, 0);
    PH_SYNC_MFMA(2)
    __builtin_amdgcn_s_barrier();

    af[0][0]=rdA(0,6,0); af[0][1]=rdA(0,6,1); af[1][0]=rdA(0,7,0); af[1][1]=rdA(0,7,1);
    if (!last) stage(1, kt+2, 1, 0);
    PH_SYNC_MFMA(3)
    if (last) { asm volatile("s_waitcnt vmcnt(0)" ::: "memory"); }
    else      { asm volatile("s_waitcnt vmcnt(4)" ::: "memory"); }
    __builtin_amdgcn_s_barrier();

    // ---- odd tile (buf1) ----
#pragma unroll
    for (int j = 0; j < 4; ++j){ bfr[j][0]=rdB(1,j,0); bfr[j][1]=rdB(1,j,1); }
    af[0][0]=rdA(1,0,0); af[0][1]=rdA(1,0,1); af[1][0]=rdA(1,1,0); af[1][1]=rdA(1,1,1);
    if (!last) stage(0, kt+2, 0, 0);
    PH_SYNC_MFMA(0)
    __builtin_amdgcn_s_barrier();

    af[0][0]=rdA(1,2,0); af[0][1]=rdA(1,2,1); af[1][0]=rdA(1,3,0); af[1][1]=rdA(1,3,1);
    if (!last) stage(0, kt+2, 1, 0);
    PH_SYNC_MFMA(1)
    __builtin_amdgcn_s_barrier();

    af[0][0]=rdA(1,4,0); af[0][1]=rdA(1,4,1); af[1][0]=rdA(1,5,0); af[1][1]=rdA(1,5,1);
    if (!last) stage(1, kt+3, 0, 1);
    PH_SYNC_MFMA(2)
    __builtin_amdgcn_s_barrier();

    af[0][0]=rdA(1,6,0); af[0][1]=rdA(1,6,1); af[1][0]=rdA(1,7,0); af[1][1]=rdA(1,7,1);
    if (!last) stage(1, kt+3, 1, 1);
    PH_SYNC_MFMA(3)
    if (last) { asm volatile("s_waitcnt vmcnt(0)" ::: "memory"); }
    else      { asm volatile("s_waitcnt vmcnt(4)" ::: "memory"); }
    __builtin_amdgcn_s_barrier();
  }
#undef PH_SYNC_MFMA
}

// ---------------------------------------------------------------- GEMM1: QKV (256^2 tiles)
__global__ __launch_bounds__(512, 2) void gemm_qkv(
    const unsigned short* __restrict__ A, const unsigned short* __restrict__ W,
    const float* __restrict__ qb, const float* __restrict__ vb,
    unsigned short* __restrict__ qg, unsigned short* __restrict__ kg,
    unsigned short* __restrict__ vt)
{
  __shared__ __align__(16) unsigned short lds[65536];   // 128 KiB
  f32x4 acc[8][4] = {};
  const int bid = blockIdx.x;                 // 480 = 20 x 24
  const int swz = (bid & 7)*60 + (bid >> 3);  // bijective XCD swizzle
  const int mt = swz / 24, ntt = swz % 24;
  const int m0 = mt << 8, n0 = ntt << 8;
  gemm8p(A, W, lds, m0, n0, acc);

  const int tid = threadIdx.x;
  const int w = tid >> 6, lane = tid & 63, g = lane >> 4, lr = lane & 15;
  const int wm = w >> 2, wn = w & 3;
  const int part = n0 >> 11;                  // 0=q 1=k 2=v
  const int b = (m0 >= LPAD) ? 1 : 0;
  const int l0 = m0 - b*LPAD;
  const int colbase = (n0 & 2047) + wn*64;
#pragma unroll
  for (int i = 0; i < 8; ++i){
    const int mloc = wm*128 + i*16 + (g << 2);
#pragma unroll
    for (int j = 0; j < 4; ++j){
      const int col = colbase + j*16 + lr;
      const int hb = col >> 7, d = col & 127;
      const float bias = (part == 0) ? qb[col] : ((part == 2) ? vb[col] : 0.f);
      const f32x4 v = acc[i][j];
      if (part == 2){
        ushort4 o;
        o.x = bf16c(v[0] + bias); o.y = bf16c(v[1] + bias);
        o.z = bf16c(v[2] + bias); o.w = bf16c(v[3] + bias);
        *(ushort4*)(vt + ((size_t)((b*NH + hb)*HD + d))*LPAD + l0 + mloc) = o;
      } else {
        unsigned short* dst = (part ? kg : qg) + (((size_t)(b*NH + hb)*LPAD) + l0 + mloc)*HD + d;
        dst[0]     = bf16c(v[0] + bias);
        dst[HD]    = bf16c(v[1] + bias);
        dst[2*HD]  = bf16c(v[2] + bias);
        dst[3*HD]  = bf16c(v[3] + bias);
      }
    }
  }
}

// ---------------------------------------------------------------- GEMM2: proj (256^2 tiles)
__global__ __launch_bounds__(512, 2) void gemm_proj(
    const unsigned short* __restrict__ A, const unsigned short* __restrict__ W,
    const float* __restrict__ pbias, float* __restrict__ out)
{
  __shared__ __align__(16) unsigned short lds[65536];
  f32x4 acc[8][4] = {};
  const int bid = blockIdx.x;                 // 160 = 20 x 8
  const int swz = (bid & 7)*20 + (bid >> 3);
  const int mt = swz >> 3, ntt = swz & 7;
  const int m0 = mt << 8, n0 = ntt << 8;
  gemm8p(A, W, lds, m0, n0, acc);

  const int tid = threadIdx.x;
  const int w = tid >> 6, lane = tid & 63, g = lane >> 4, lr = lane & 15;
  const int wm = w >> 2, wn = w & 3;
  const int b = (m0 >= LPAD) ? 1 : 0;
  const int l0 = m0 - b*LPAD;
#pragma unroll
  for (int i = 0; i < 8; ++i){
    const int mloc = wm*128 + i*16 + (g << 2);
#pragma unroll
    for (int j = 0; j < 4; ++j){
      const int n = n0 + wn*64 + j*16 + lr;
      const float bias = pbias[n];
      const f32x4 v = acc[i][j];
#pragma unroll
      for (int r = 0; r < 4; ++r){
        const int l = l0 + mloc + r;
        if (l < SEQL) out[(((size_t)(b*SEQL + l)) << 11) + n] = v[r] + bias;
      }
    }
  }
}

// ---------------------------------------------------------------- rope + norm
__global__ __launch_bounds__(256) void rope_norm(
    unsigned short* __restrict__ qg, unsigned short* __restrict__ kg,
    const float* __restrict__ rope, const float* __restrict__ smlog)
{
  const int sub = threadIdx.x & 15;
  const int l = blockIdx.x*16 + (threadIdx.x >> 4);
  if (l >= SEQL) return;
  const int pb = blockIdx.y;
  const int part = pb >> 5, bh = pb & 31, h = bh & 15;
  unsigned short* base = (part ? kg : qg) + ((long)bh*LPAD + l)*HD + (sub << 3);
  const u16x8 v = *(const u16x8*)base;
  float f[8];
#pragma unroll
  for (int i = 0; i < 8; ++i) f[i] = bf2f(v[i]);
  float ss = 0.f;
#pragma unroll
  for (int i = 0; i < 8; ++i) ss += f[i]*f[i];
  ss += __shfl_xor(ss, 1, 16);
  ss += __shfl_xor(ss, 2, 16);
  ss += __shfl_xor(ss, 4, 16);
  ss += __shfl_xor(ss, 8, 16);
  float inv = 1.f / fmaxf(sqrtf(ss), 1e-12f);
  if (part == 0){
    float sl = fminf(smlog[h], 4.605170185988091f);
    inv *= __expf(sl) * 1.4426950408889634f;          // fold log2(e)
  }
  const float4 cs = *(const float4*)(rope + (long)l*64 + (sub << 2));
  const float4 sn = *(const float4*)(rope + (long)(SEQL + l)*64 + (sub << 2));
  u16x8 o;
  const float c4[4] = {cs.x, cs.y, cs.z, cs.w};
  const float s4[4] = {sn.x, sn.y, sn.z, sn.w};
#pragma unroll
  for (int p = 0; p < 4; ++p){
    const float re = f[2*p], im = f[2*p+1];
    o[2*p]   = bf16c((c4[p]*re - s4[p]*im)*inv);
    o[2*p+1] = bf16c((s4[p]*re + c4[p]*im)*inv);
  }
  *(u16x8*)base = o;
}

// ---------------------------------------------------------------- attention
static __device__ __forceinline__ int q_end_of(int q){
  if (q >= SEQL) return 1;
  if (q < 121){
    if (q < 1) return 1;
    if (q < 5) return 5;
    if (q < 21) return 21;
    if (q < 57) return 57;
    return 121;
  }
  if (q < 265) return 265;
  if (q < 521) return 521;
  if (q < 921) return 921;
  if (q < 1497) return 1497;
  return 2521;
}

__global__ __launch_bounds__(512) void attn_kernel(
    const unsigned short* __restrict__ qg, const unsigned short* __restrict__ kg,
    const unsigned short* __restrict__ vt, unsigned short* __restrict__ aout)
{
  __shared__ __align__(16) unsigned short Ks[64*128];
  __shared__ __align__(16) unsigned short Vs[128*64];
  __shared__ __align__(16) unsigned short Ps[8][16*72];
  const int tid = threadIdx.x, w = tid >> 6, lane = tid & 63;
  const int g = lane >> 4, lr = lane & 15;
  const int qt = (int)gridDim.x - 1 - (int)blockIdx.x;
  const int bh = blockIdx.y;
  const int q0 = qt << 7, qw = q0 + (w << 4);
  const long kvBase = (long)bh * LPAD * HD;

  u16x8 qf[4];
  {
    const unsigned short* qrow = qg + kvBase + (long)(qw + lr)*HD + (g << 3);
#pragma unroll
    for (int c = 0; c < 4; ++c) qf[c] = *(const u16x8*)(qrow + (c << 5));
  }
  const int qe  = q_end_of(qw + lr);
  const int qe0 = q_end_of(qw);
  const int qmax = (q0 + 127 < SEQL - 1) ? q0 + 127 : SEQL - 1;
  const int nt = (q_end_of(qmax) + 63) >> 6;

  float m2 = -1e30f, l_run = 0.f;
  f32x4 acco[8] = {};

  for (int t = 0; t < nt; ++t){
    __syncthreads();
    const int kvb = t << 6;
#pragma unroll
    for (int c = 0; c < 2; ++c){
      const int idx = (c << 9) + tid;
      const int kv = idx >> 4, ch = idx & 15;
      glds16(kg + kvBase + (long)(kvb + kv)*HD + ((ch ^ (kv & 7)) << 3),
             Ks + (c << 12) + (w << 9));
      const int dd = idx >> 3, ch2 = idx & 7;
      glds16(vt + kvBase + (long)dd*LPAD + kvb + ((ch2 ^ (dd & 7)) << 3),
             Vs + (c << 12) + (w << 9));
    }
    __syncthreads();

    f32x4 accs[4] = {};
    __builtin_amdgcn_s_setprio(1);
#pragma unroll
    for (int mf = 0; mf < 4; ++mf){
      const int kvr = (mf << 4) + lr;
      const unsigned short* krow = Ks + kvr*HD;
      const int sw = kvr & 7;
#pragma unroll
      for (int c = 0; c < 4; ++c){
        u16x8 kf = *(const u16x8*)(krow + ((((c << 2) + g) ^ sw) << 3));
        accs[mf] = __builtin_amdgcn_mfma_f32_16x16x32_bf16(asbf(kf), asbf(qf[c]), accs[mf], 0, 0, 0);
      }
    }
    __builtin_amdgcn_s_setprio(0);

    float tmax = -1e30f;
    if (kvb + 64 <= qe0){
#pragma unroll
      for (int mf = 0; mf < 4; ++mf)
#pragma unroll
        for (int r = 0; r < 4; ++r) tmax = fmaxf(tmax, accs[mf][r]);
    } else {
#pragma unroll
      for (int mf = 0; mf < 4; ++mf){
#pragma unroll
        for (int r = 0; r < 4; ++r){
          const int kvg = kvb + (mf << 4) + (g << 2) + r;
          float s = (kvg < qe) ? accs[mf][r] : -1e30f;
          accs[mf][r] = s;
          tmax = fmaxf(tmax, s);
        }
      }
    }
    tmax = fmaxf(tmax, __shfl_xor(tmax, 16, 64));
    tmax = fmaxf(tmax, __shfl_xor(tmax, 32, 64));

    float alpha = 1.f;
    const bool need = !__all(tmax <= m2 + 11.0f);
    if (need){
      const float mnew = fmaxf(m2, tmax);
      alpha = exp2f(m2 - mnew);
      m2 = mnew;
      const float a0 = __shfl(alpha, (g << 2) + 0, 64);
      const float a1 = __shfl(alpha, (g << 2) + 1, 64);
      const float a2 = __shfl(alpha, (g << 2) + 2, 64);
      const float a3 = __shfl(alpha, (g << 2) + 3, 64);
#pragma unroll
      for (int nf = 0; nf < 8; ++nf){
        acco[nf][0] *= a0; acco[nf][1] *= a1; acco[nf][2] *= a2; acco[nf][3] *= a3;
      }
    }

    float tsum = 0.f;
#pragma unroll
    for (int mf = 0; mf < 4; ++mf){
#pragma unroll
      for (int r = 0; r < 4; ++r){
        const float p = exp2f(accs[mf][r] - m2);
        accs[mf][r] = p;
        tsum += p;
      }
    }
    tsum += __shfl_xor(tsum, 16, 64);
    tsum += __shfl_xor(tsum, 32, 64);
    l_run = l_run*alpha + tsum;

    unsigned short* prow = &Ps[w][lr*72 + (g << 2)];
#pragma unroll
    for (int mf = 0; mf < 4; ++mf){
      uint2 pk;
      pk.x = (unsigned)bf16c(accs[mf][0]) | ((unsigned)bf16c(accs[mf][1]) << 16);
      pk.y = (unsigned)bf16c(accs[mf][2]) | ((unsigned)bf16c(accs[mf][3]) << 16);
      *(uint2*)(prow + (mf << 4)) = pk;
    }

    __builtin_amdgcn_s_setprio(1);
#pragma unroll
    for (int c = 0; c < 2; ++c){
      u16x8 pf = *(const u16x8*)(&Ps[w][lr*72 + (c << 5) + (g << 3)]);
      const int sw2 = lr & 7;
#pragma unroll
      for (int nf = 0; nf < 8; ++nf){
        u16x8 vf = *(const u16x8*)(Vs + ((nf << 4) + lr)*64 + ((((c << 2) + g) ^ sw2) << 3));
        acco[nf] = __builtin_amdgcn_mfma_f32_16x16x32_bf16(asbf(pf), asbf(vf), acco[nf], 0, 0, 0);
      }
    }
    __builtin_amdgcn_s_setprio(0);
  }

  const float rcp = 1.f / l_run;
  const float li0 = __shfl(rcp, (g << 2) + 0, 64);
  const float li1 = __shfl(rcp, (g << 2) + 1, 64);
  const float li2 = __shfl(rcp, (g << 2) + 2, 64);
  const float li3 = __shfl(rcp, (g << 2) + 3, 64);
  const int b = bh >> 4, h = bh & 15;
#pragma unroll
  for (int r = 0; r < 4; ++r){
    const int qq = qw + (g << 2) + r;
    if (qq < SEQL){
      const float lir = (r == 0) ? li0 : ((r == 1) ? li1 : ((r == 2) ? li2 : li3));
      unsigned short* dst = aout + (((long)(b*LPAD + qq)) << 11) + (h << 7) + lr;
#pragma unroll
      for (int nf = 0; nf < 8; ++nf)
        dst[nf << 4] = bf16c(acco[nf][r] * lir);
    }
  }
}

// ---------------------------------------------------------------- launch
extern "C" void kernel_launch(void* const* d_in, const int* in_sizes, int n_in,
                              void* d_out, int out_size, void* d_ws, size_t ws_size,
                              hipStream_t stream) {
  const float* x     = (const float*)d_in[0];
  const float* wqkv  = (const float*)d_in[1];
  const float* qb    = (const float*)d_in[2];
  const float* vb    = (const float*)d_in[3];
  const float* smlog = (const float*)d_in[4];
  const float* projw = (const float*)d_in[5];
  const float* projb = (const float*)d_in[6];
  const float* rope  = (const float*)d_in[7];
  float* out = (float*)d_out;

  unsigned short* xb = (unsigned short*)d_ws;
  unsigned short* wb = xb + (size_t)NB*LPAD*CD;
  unsigned short* pw = wb + (size_t)3*CD*CD;
  unsigned short* qg = pw + (size_t)CD*CD;
  unsigned short* kg = qg + (size_t)NB*NH*LPAD*HD;
  unsigned short* vt = kg + (size_t)NB*NH*LPAD*HD;

  prep_kernel<<<2048, 256, 0, stream>>>(x, wqkv, projw, xb, wb, pw);
  gemm_qkv<<<480, 512, 0, stream>>>(xb, wb, qb, vb, qg, kg, vt);
  rope_norm<<<dim3(158, 64), 256, 0, stream>>>(qg, kg, rope, smlog);
  attn_kernel<<<dim3(20, 32), 512, 0, stream>>>(qg, kg, vt, xb);
  gemm_proj<<<160, 512, 0, stream>>>(xb, pw, projb, out);
}

// Round 4
// 525.063 us; speedup vs baseline: 1.1630x; 1.0194x over previous
//
#include <hip/hip_runtime.h>
#include <stdint.h>

#define SEQL 2521
#define LPAD 2560
#define NB 2
#define NH 16
#define HD 128
#define CD 2048
#define KD 2048

typedef float f32x4 __attribute__((ext_vector_type(4)));
typedef __bf16 bf16x8 __attribute__((ext_vector_type(8)));
typedef unsigned short u16x8 __attribute__((ext_vector_type(8)));

static __device__ __forceinline__ unsigned short bf16c(float f){
  __bf16 h = (__bf16)f;
  return __builtin_bit_cast(unsigned short, h);
}
static __device__ __forceinline__ float bf2f(unsigned short s){
  union { unsigned u; float f; } v; v.u = ((unsigned)s) << 16; return v.f;
}
static __device__ __forceinline__ bf16x8 asbf(u16x8 v){ return __builtin_bit_cast(bf16x8, v); }

typedef const __attribute__((address_space(1))) unsigned int* gas1_t;
typedef __attribute__((address_space(3))) unsigned int* las3_t;
static __device__ __forceinline__ void glds16(const void* g, void* l){
  __builtin_amdgcn_global_load_lds((gas1_t)g, (las3_t)l, 16, 0, 0);
}

// ---------------------------------------------------------------- prep
__global__ __launch_bounds__(256) void prep_kernel(
    const float* __restrict__ x, const float* __restrict__ wqkv, const float* __restrict__ projw,
    unsigned short* __restrict__ xb, unsigned short* __restrict__ wb, unsigned short* __restrict__ pw)
{
  const int NX = (NB*LPAD*CD)/4;
  const int NW = (3*CD*CD)/4;
  const int NPj = (CD*CD)/4;
  const int total = NX + NW + NPj;
  for (int v = blockIdx.x*256 + threadIdx.x; v < total; v += gridDim.x*256){
    if (v < NX){
      int e = v << 2;
      int row = e >> 11, col = e & 2047;
      int b = (row >= LPAD) ? 1 : 0;
      int l = row - b*LPAD;
      ushort4 o;
      if (l < SEQL){
        const float4 f = *(const float4*)(x + (((long)(b*SEQL + l)) << 11) + col);
        o.x = bf16c(f.x); o.y = bf16c(f.y); o.z = bf16c(f.z); o.w = bf16c(f.w);
      } else { o.x = 0; o.y = 0; o.z = 0; o.w = 0; }
      *(ushort4*)(xb + e) = o;
    } else if (v < NX + NW){
      long i = (long)(v - NX) << 2;
      const float4 f = *(const float4*)(wqkv + i);
      ushort4 o; o.x=bf16c(f.x); o.y=bf16c(f.y); o.z=bf16c(f.z); o.w=bf16c(f.w);
      *(ushort4*)(wb + i) = o;
    } else {
      long i = (long)(v - NX - NW) << 2;
      const float4 f = *(const float4*)(projw + i);
      ushort4 o; o.x=bf16c(f.x); o.y=bf16c(f.y); o.z=bf16c(f.z); o.w=bf16c(f.w);
      *(ushort4*)(pw + i) = o;
    }
  }
}

// ---------------------------------------------------------------- 8-phase 256x256 GEMM core
static __device__ __forceinline__ void gemm8p(
    const unsigned short* __restrict__ A, const unsigned short* __restrict__ Bm,
    unsigned short* lds, int m0, int n0, f32x4 acc[8][4])
{
  const int tid = threadIdx.x;
  const int w = tid >> 6, lane = tid & 63;
  const int g = lane >> 4, lr = lane & 15;
  const int wm = w >> 2, wn = w & 3;
  const int xorv = (lr & 7) << 3;
  const int off0 = (g << 3) ^ xorv;
  const int arow = wm*128 + lr;
  const int brow = wn*64 + lr;

  auto stage = [&](int mat, int kt, int half, int buf){
    const unsigned short* G = mat ? Bm : A;
    const int base0 = mat ? n0 : m0;
    unsigned short* lb = lds + buf*32768 + mat*16384;
#pragma unroll
    for (int p = 0; p < 2; ++p){
      const int cb_ = (half<<10) + (p<<9) + (w<<6);
      const int c = cb_ + lane;
      const int row = c >> 3, cc = c & 7;
      glds16(G + (size_t)(base0 + row)*KD + (kt<<6) + ((cc ^ (row & 7)) << 3),
             lb + (cb_ << 3));
    }
  };
  auto rdA = [&](int buf, int i, int ks)->u16x8 {
    return *(const u16x8*)(lds + buf*32768 + (arow + i*16)*64 + (off0 ^ (ks<<5)));
  };
  auto rdB = [&](int buf, int j, int ks)->u16x8 {
    return *(const u16x8*)(lds + buf*32768 + 16384 + (brow + j*16)*64 + (off0 ^ (ks<<5)));
  };

  u16x8 bfr[4][2], af[2][2];
  auto mfma16 = [&](int q){
#pragma unroll
    for (int i2 = 0; i2 < 2; ++i2)
#pragma unroll
      for (int ks = 0; ks < 2; ++ks)
#pragma unroll
        for (int j = 0; j < 4; ++j)
          acc[2*q+i2][j] = __builtin_amdgcn_mfma_f32_16x16x32_bf16(
              asbf(af[i2][ks]), asbf(bfr[j][ks]), acc[2*q+i2][j], 0, 0, 0);
  };

#define PH_SYNC_MFMA(Q) \
    __builtin_amdgcn_s_barrier(); \
    asm volatile("s_waitcnt lgkmcnt(0)" ::: "memory"); \
    __builtin_amdgcn_s_setprio(1); mfma16(Q); __builtin_amdgcn_s_setprio(0);

  stage(0, 0, 0, 0); stage(0, 0, 1, 0);
  stage(1, 0, 0, 0); stage(1, 0, 1, 0);
  stage(1, 1, 0, 1); stage(1, 1, 1, 1);
  asm volatile("s_waitcnt vmcnt(4)" ::: "memory");
  __builtin_amdgcn_s_barrier();

  const int NI = KD >> 7;
  for (int it = 0; it < NI; ++it){
    const int kt = it << 1;
    const bool last = (it == NI-1);
#pragma unroll
    for (int j = 0; j < 4; ++j){ bfr[j][0]=rdB(0,j,0); bfr[j][1]=rdB(0,j,1); }
    af[0][0]=rdA(0,0,0); af[0][1]=rdA(0,0,1); af[1][0]=rdA(0,1,0); af[1][1]=rdA(0,1,1);
    stage(0, kt+1, 0, 1);
    PH_SYNC_MFMA(0)
    __builtin_amdgcn_s_barrier();

    af[0][0]=rdA(0,2,0); af[0][1]=rdA(0,2,1); af[1][0]=rdA(0,3,0); af[1][1]=rdA(0,3,1);
    stage(0, kt+1, 1, 1);
    PH_SYNC_MFMA(1)
    __builtin_amdgcn_s_barrier();

    af[0][0]=rdA(0,4,0); af[0][1]=rdA(0,4,1); af[1][0]=rdA(0,5,0); af[1][1]=rdA(0,5,1);
    if (!last) stage(1, kt+2, 0, 0);
    PH_SYNC_MFMA(2)
    __builtin_amdgcn_s_barrier();

    af[0][0]=rdA(0,6,0); af[0][1]=rdA(0,6,1); af[1][0]=rdA(0,7,0); af[1][1]=rdA(0,7,1);
    if (!last) stage(1, kt+2, 1, 0);
    PH_SYNC_MFMA(3)
    if (last) { asm volatile("s_waitcnt vmcnt(0)" ::: "memory"); }
    else      { asm volatile("s_waitcnt vmcnt(4)" ::: "memory"); }
    __builtin_amdgcn_s_barrier();

#pragma unroll
    for (int j = 0; j < 4; ++j){ bfr[j][0]=rdB(1,j,0); bfr[j][1]=rdB(1,j,1); }
    af[0][0]=rdA(1,0,0); af[0][1]=rdA(1,0,1); af[1][0]=rdA(1,1,0); af[1][1]=rdA(1,1,1);
    if (!last) stage(0, kt+2, 0, 0);
    PH_SYNC_MFMA(0)
    __builtin_amdgcn_s_barrier();

    af[0][0]=rdA(1,2,0); af[0][1]=rdA(1,2,1); af[1][0]=rdA(1,3,0); af[1][1]=rdA(1,3,1);
    if (!last) stage(0, kt+2, 1, 0);
    PH_SYNC_MFMA(1)
    __builtin_amdgcn_s_barrier();

    af[0][0]=rdA(1,4,0); af[0][1]=rdA(1,4,1); af[1][0]=rdA(1,5,0); af[1][1]=rdA(1,5,1);
    if (!last) stage(1, kt+3, 0, 1);
    PH_SYNC_MFMA(2)
    __builtin_amdgcn_s_barrier();

    af[0][0]=rdA(1,6,0); af[0][1]=rdA(1,6,1); af[1][0]=rdA(1,7,0); af[1][1]=rdA(1,7,1);
    if (!last) stage(1, kt+3, 1, 1);
    PH_SYNC_MFMA(3)
    if (last) { asm volatile("s_waitcnt vmcnt(0)" ::: "memory"); }
    else      { asm volatile("s_waitcnt vmcnt(4)" ::: "memory"); }
    __builtin_amdgcn_s_barrier();
  }
#undef PH_SYNC_MFMA
}

// ---------------------------------------------------------------- GEMM1: QKV
__global__ __launch_bounds__(512, 2) void gemm_qkv(
    const unsigned short* __restrict__ A, const unsigned short* __restrict__ W,
    const float* __restrict__ qb, const float* __restrict__ vb,
    unsigned short* __restrict__ qg, unsigned short* __restrict__ kg,
    unsigned short* __restrict__ vt)
{
  __shared__ __align__(16) unsigned short lds[65536];
  f32x4 acc[8][4] = {};
  const int bid = blockIdx.x;
  const int swz = (bid & 7)*60 + (bid >> 3);
  const int mt = swz / 24, ntt = swz % 24;
  const int m0 = mt << 8, n0 = ntt << 8;
  gemm8p(A, W, lds, m0, n0, acc);

  const int tid = threadIdx.x;
  const int w = tid >> 6, lane = tid & 63, g = lane >> 4, lr = lane & 15;
  const int wm = w >> 2, wn = w & 3;
  const int part = n0 >> 11;
  const int b = (m0 >= LPAD) ? 1 : 0;
  const int l0 = m0 - b*LPAD;
  const int colbase = (n0 & 2047) + wn*64;
#pragma unroll
  for (int i = 0; i < 8; ++i){
    const int mloc = wm*128 + i*16 + (g << 2);
#pragma unroll
    for (int j = 0; j < 4; ++j){
      const int col = colbase + j*16 + lr;
      const int hb = col >> 7, d = col & 127;
      const float bias = (part == 0) ? qb[col] : ((part == 2) ? vb[col] : 0.f);
      const f32x4 v = acc[i][j];
      if (part == 2){
        ushort4 o;
        o.x = bf16c(v[0] + bias); o.y = bf16c(v[1] + bias);
        o.z = bf16c(v[2] + bias); o.w = bf16c(v[3] + bias);
        *(ushort4*)(vt + ((size_t)((b*NH + hb)*HD + d))*LPAD + l0 + mloc) = o;
      } else {
        unsigned short* dst = (part ? kg : qg) + (((size_t)(b*NH + hb)*LPAD) + l0 + mloc)*HD + d;
        dst[0]     = bf16c(v[0] + bias);
        dst[HD]    = bf16c(v[1] + bias);
        dst[2*HD]  = bf16c(v[2] + bias);
        dst[3*HD]  = bf16c(v[3] + bias);
      }
    }
  }
}

// ---------------------------------------------------------------- GEMM2: proj
__global__ __launch_bounds__(512, 2) void gemm_proj(
    const unsigned short* __restrict__ A, const unsigned short* __restrict__ W,
    const float* __restrict__ pbias, float* __restrict__ out)
{
  __shared__ __align__(16) unsigned short lds[65536];
  f32x4 acc[8][4] = {};
  const int bid = blockIdx.x;
  const int swz = (bid & 7)*20 + (bid >> 3);
  const int mt = swz >> 3, ntt = swz & 7;
  const int m0 = mt << 8, n0 = ntt << 8;
  gemm8p(A, W, lds, m0, n0, acc);

  const int tid = threadIdx.x;
  const int w = tid >> 6, lane = tid & 63, g = lane >> 4, lr = lane & 15;
  const int wm = w >> 2, wn = w & 3;
  const int b = (m0 >= LPAD) ? 1 : 0;
  const int l0 = m0 - b*LPAD;
#pragma unroll
  for (int i = 0; i < 8; ++i){
    const int mloc = wm*128 + i*16 + (g << 2);
#pragma unroll
    for (int j = 0; j < 4; ++j){
      const int n = n0 + wn*64 + j*16 + lr;
      const float bias = pbias[n];
      const f32x4 v = acc[i][j];
#pragma unroll
      for (int r = 0; r < 4; ++r){
        const int l = l0 + mloc + r;
        if (l < SEQL) out[(((size_t)(b*SEQL + l)) << 11) + n] = v[r] + bias;
      }
    }
  }
}

// ---------------------------------------------------------------- rope + norm
__global__ __launch_bounds__(256) void rope_norm(
    unsigned short* __restrict__ qg, unsigned short* __restrict__ kg,
    const float* __restrict__ rope, const float* __restrict__ smlog)
{
  const int sub = threadIdx.x & 15;
  const int l = blockIdx.x*16 + (threadIdx.x >> 4);
  if (l >= SEQL) return;
  const int pb = blockIdx.y;
  const int part = pb >> 5, bh = pb & 31, h = bh & 15;
  unsigned short* base = (part ? kg : qg) + ((long)bh*LPAD + l)*HD + (sub << 3);
  const u16x8 v = *(const u16x8*)base;
  float f[8];
#pragma unroll
  for (int i = 0; i < 8; ++i) f[i] = bf2f(v[i]);
  float ss = 0.f;
#pragma unroll
  for (int i = 0; i < 8; ++i) ss += f[i]*f[i];
  ss += __shfl_xor(ss, 1, 16);
  ss += __shfl_xor(ss, 2, 16);
  ss += __shfl_xor(ss, 4, 16);
  ss += __shfl_xor(ss, 8, 16);
  float inv = 1.f / fmaxf(sqrtf(ss), 1e-12f);
  if (part == 0){
    float sl = fminf(smlog[h], 4.605170185988091f);
    inv *= __expf(sl) * 1.4426950408889634f;          // fold log2(e)
  }
  const float4 cs = *(const float4*)(rope + (long)l*64 + (sub << 2));
  const float4 sn = *(const float4*)(rope + (long)(SEQL + l)*64 + (sub << 2));
  u16x8 o;
  const float c4[4] = {cs.x, cs.y, cs.z, cs.w};
  const float s4[4] = {sn.x, sn.y, sn.z, sn.w};
#pragma unroll
  for (int p = 0; p < 4; ++p){
    const float re = f[2*p], im = f[2*p+1];
    o[2*p]   = bf16c((c4[p]*re - s4[p]*im)*inv);
    o[2*p+1] = bf16c((s4[p]*re + c4[p]*im)*inv);
  }
  *(u16x8*)base = o;
}

// ---------------------------------------------------------------- attention
static __device__ __forceinline__ int q_end_of(int q){
  if (q >= SEQL) return 1;
  if (q < 121){
    if (q < 1) return 1;
    if (q < 5) return 5;
    if (q < 21) return 21;
    if (q < 57) return 57;
    return 121;
  }
  if (q < 265) return 265;
  if (q < 521) return 521;
  if (q < 921) return 921;
  if (q < 1497) return 1497;
  return 2521;
}

// 4 waves x 32 q-rows = 128 q-rows per block; KV tile 64, double-buffered.
// Permuted-K QK^T: lane (lr,g) accs[mf][r] = S[q][kv = 8g + 4(mf&1) + r + 32(mf>>1)]
// -> P fragments for PV are formed fully in-register (no P LDS round-trip).
__global__ __launch_bounds__(256, 2) void attn_kernel(
    const unsigned short* __restrict__ qg, const unsigned short* __restrict__ kg,
    const unsigned short* __restrict__ vt, unsigned short* __restrict__ aout)
{
  __shared__ __align__(16) unsigned short Ks[2*64*128];  // [buf][kv][hd], chunk^f_K(kv)
  __shared__ __align__(16) unsigned short Vs[2*128*64];  // [buf][d][kv],  chunk^(d&7)
  const int tid = threadIdx.x, w = tid >> 6, lane = tid & 63;
  const int g = lane >> 4, lr = lane & 15, lr7 = lr & 7;
  const int qt = (int)gridDim.x - 1 - (int)blockIdx.x;   // longest blocks first
  const int bh = blockIdx.y;
  const int q0 = qt << 7, qw = q0 + (w << 5);            // wave owns 32 q-rows
  const long kvBase = (long)bh * LPAD * HD;

  u16x8 qfA[4], qfB[4];
  {
    const unsigned short* qrow = qg + kvBase + (long)(qw + lr)*HD + (g << 3);
#pragma unroll
    for (int c = 0; c < 4; ++c) qfA[c] = *(const u16x8*)(qrow + (c << 5));
    const unsigned short* qrow2 = qrow + (long)16*HD;
#pragma unroll
    for (int c = 0; c < 4; ++c) qfB[c] = *(const u16x8*)(qrow2 + (c << 5));
  }
  const int qeA = q_end_of(qw + lr);
  const int qeB = q_end_of(qw + 16 + lr);
  const int qe0 = q_end_of(qw);                          // min over wave
  const int qmax = (q0 + 127 < SEQL - 1) ? q0 + 127 : SEQL - 1;
  const int nt = (q_end_of(qmax) + 63) >> 6;

  float m2A = -1e30f, lA = 0.f, m2B = -1e30f, lB = 0.f;
  f32x4 oA[8] = {}, oB[8] = {};

  auto stageKV = [&](int t, int buf){
    const int kvb2 = t << 6;
#pragma unroll
    for (int c = 0; c < 4; ++c){
      const int cb = (c << 8) + tid;                     // 0..1023 K chunks
      const int row = cb >> 4, cc = cb & 15;
      const int fk = (row & 3) | (((row >> 3) & 1) << 2);
      const int sc = (cc & 8) | ((cc & 7) ^ fk);
      glds16(kg + kvBase + (size_t)(kvb2 + row)*HD + (sc << 3),
             Ks + buf*8192 + (((c << 8) + (w << 6)) << 3));
    }
#pragma unroll
    for (int c = 0; c < 4; ++c){
      const int cb = (c << 8) + tid;                     // 0..1023 V chunks
      const int d = cb >> 3, cc = cb & 7;
      const int sc = cc ^ (d & 7);
      glds16(vt + kvBase + (size_t)d*LPAD + kvb2 + (sc << 3),
             Vs + buf*8192 + (((c << 8) + (w << 6)) << 3));
    }
  };

  stageKV(0, 0);

  for (int t = 0; t < nt; ++t){
    __builtin_amdgcn_s_barrier();                        // protect buf overwrite
    const bool pf = (t + 1 < nt);
    if (pf){
      stageKV(t + 1, (t + 1) & 1);
      asm volatile("s_waitcnt vmcnt(8)" ::: "memory");   // tile t resident
    } else {
      asm volatile("s_waitcnt vmcnt(0)" ::: "memory");
    }
    __builtin_amdgcn_s_barrier();                        // all waves' chunks landed

    const unsigned short* Kb = Ks + (t & 1)*8192;
    const unsigned short* Vb = Vs + (t & 1)*8192;
    const int kvb = t << 6;

    // ---- QK^T (permuted K rows) ----
    f32x4 sA[4] = {}, sB[4] = {};
    __builtin_amdgcn_s_setprio(1);
#pragma unroll
    for (int mf = 0; mf < 4; ++mf){
      const int kvr = ((mf & 1) << 2) + ((mf >> 1) << 5) + ((lr >> 2) << 3) + (lr & 3);
      const unsigned short* kr = Kb + kvr*HD;
#pragma unroll
      for (int c = 0; c < 4; ++c){
        const int cc = (c << 2) + g;
        const int swz = (cc & 8) | ((cc & 7) ^ lr7);
        const u16x8 kf = *(const u16x8*)(kr + (swz << 3));
        sA[mf] = __builtin_amdgcn_mfma_f32_16x16x32_bf16(asbf(kf), asbf(qfA[c]), sA[mf], 0, 0, 0);
        sB[mf] = __builtin_amdgcn_mfma_f32_16x16x32_bf16(asbf(kf), asbf(qfB[c]), sB[mf], 0, 0, 0);
      }
    }
    __builtin_amdgcn_s_setprio(0);

    const bool fullvis = (kvb + 64 <= qe0);

#define SM_STEP(SS, M2, LL, OO, QEL, ALPHA) { \
    float tmax = -1e30f; \
    if (fullvis){ \
      _Pragma("unroll") for (int mf = 0; mf < 4; ++mf) \
        _Pragma("unroll") for (int r = 0; r < 4; ++r) tmax = fmaxf(tmax, SS[mf][r]); \
    } else { \
      _Pragma("unroll") for (int mf = 0; mf < 4; ++mf){ \
        _Pragma("unroll") for (int r = 0; r < 4; ++r){ \
          const int kvg = kvb + (g << 3) + ((mf & 1) << 2) + r + ((mf >> 1) << 5); \
          float s_ = (kvg < QEL) ? SS[mf][r] : -1e30f; \
          SS[mf][r] = s_; tmax = fmaxf(tmax, s_); \
        } \
      } \
    } \
    tmax = fmaxf(tmax, __shfl_xor(tmax, 16, 64)); \
    tmax = fmaxf(tmax, __shfl_xor(tmax, 32, 64)); \
    float ALPHA = 1.f; \
    if (!__all(tmax <= M2 + 11.0f)){ \
      const float mnew = fmaxf(M2, tmax); \
      ALPHA = exp2f(M2 - mnew); M2 = mnew; \
      const float a0 = __shfl(ALPHA, (g << 2) + 0, 64); \
      const float a1 = __shfl(ALPHA, (g << 2) + 1, 64); \
      const float a2 = __shfl(ALPHA, (g << 2) + 2, 64); \
      const float a3 = __shfl(ALPHA, (g << 2) + 3, 64); \
      _Pragma("unroll") for (int nf = 0; nf < 8; ++nf){ \
        OO[nf][0] *= a0; OO[nf][1] *= a1; OO[nf][2] *= a2; OO[nf][3] *= a3; \
      } \
    } \
    float ts = 0.f; \
    _Pragma("unroll") for (int mf = 0; mf < 4; ++mf){ \
      _Pragma("unroll") for (int r = 0; r < 4; ++r){ \
        const float p_ = exp2f(SS[mf][r] - M2); SS[mf][r] = p_; ts += p_; \
      } \
    } \
    ts += __shfl_xor(ts, 16, 64); \
    ts += __shfl_xor(ts, 32, 64); \
    LL = LL*ALPHA + ts; }

    SM_STEP(sA, m2A, lA, oA, qeA, alphaA)
    SM_STEP(sB, m2B, lB, oB, qeB, alphaB)
#undef SM_STEP

    // ---- pack P in-register: pa[c] = {sX[2c][0..3], sX[2c+1][0..3]} ----
    u16x8 paA[2], paB[2];
#pragma unroll
    for (int c = 0; c < 2; ++c){
#pragma unroll
      for (int r = 0; r < 4; ++r){
        paA[c][r]   = bf16c(sA[2*c][r]);
        paA[c][4+r] = bf16c(sA[2*c+1][r]);
        paB[c][r]   = bf16c(sB[2*c][r]);
        paB[c][4+r] = bf16c(sB[2*c+1][r]);
      }
    }

    // ---- O += P * V ----
    __builtin_amdgcn_s_setprio(1);
#pragma unroll
    for (int c = 0; c < 2; ++c){
#pragma unroll
      for (int nf = 0; nf < 8; ++nf){
        const u16x8 vf = *(const u16x8*)(Vb + ((nf << 4) + lr)*64 + ((((c << 2) + g) ^ lr7) << 3));
        oA[nf] = __builtin_amdgcn_mfma_f32_16x16x32_bf16(asbf(paA[c]), asbf(vf), oA[nf], 0, 0, 0);
        oB[nf] = __builtin_amdgcn_mfma_f32_16x16x32_bf16(asbf(paB[c]), asbf(vf), oB[nf], 0, 0, 0);
      }
    }
    __builtin_amdgcn_s_setprio(0);
  }

  const int b = bh >> 4, h = bh & 15;
  {
    const float rcp = 1.f / lA;
    const float li0 = __shfl(rcp, (g << 2) + 0, 64);
    const float li1 = __shfl(rcp, (g << 2) + 1, 64);
    const float li2 = __shfl(rcp, (g << 2) + 2, 64);
    const float li3 = __shfl(rcp, (g << 2) + 3, 64);
#pragma unroll
    for (int r = 0; r < 4; ++r){
      const int qq = qw + (g << 2) + r;
      if (qq < SEQL){
        const float lir = (r == 0) ? li0 : ((r == 1) ? li1 : ((r == 2) ? li2 : li3));
        unsigned short* dst = aout + (((long)(b*LPAD + qq)) << 11) + (h << 7) + lr;
#pragma unroll
        for (int nf = 0; nf < 8; ++nf)
          dst[nf << 4] = bf16c(oA[nf][r] * lir);
      }
    }
  }
  {
    const float rcp = 1.f / lB;
    const float li0 = __shfl(rcp, (g << 2) + 0, 64);
    const float li1 = __shfl(rcp, (g << 2) + 1, 64);
    const float li2 = __shfl(rcp, (g << 2) + 2, 64);
    const float li3 = __shfl(rcp, (g << 2) + 3, 64);
#pragma unroll
    for (int r = 0; r < 4; ++r){
      const int qq = qw + 16 + (g << 2) + r;
      if (qq < SEQL){
        const float lir = (r == 0) ? li0 : ((r == 1) ? li1 : ((r == 2) ? li2 : li3));
        unsigned short* dst = aout + (((long)(b*LPAD + qq)) << 11) + (h << 7) + lr;
#pragma unroll
        for (int nf = 0; nf < 8; ++nf)
          dst[nf << 4] = bf16c(oB[nf][r] * lir);
      }
    }
  }
}

// ---------------------------------------------------------------- launch
extern "C" void kernel_launch(void* const* d_in, const int* in_sizes, int n_in,
                              void* d_out, int out_size, void* d_ws, size_t ws_size,
                              hipStream_t stream) {
  const float* x     = (const float*)d_in[0];
  const float* wqkv  = (const float*)d_in[1];
  const float* qb    = (const float*)d_in[2];
  const float* vb    = (const float*)d_in[3];
  const float* smlog = (const float*)d_in[4];
  const float* projw = (const float*)d_in[5];
  const float* projb = (const float*)d_in[6];
  const float* rope  = (const float*)d_in[7];
  float* out = (float*)d_out;

  unsigned short* xb = (unsigned short*)d_ws;
  unsigned short* wb = xb + (size_t)NB*LPAD*CD;
  unsigned short* pw = wb + (size_t)3*CD*CD;
  unsigned short* qg = pw + (size_t)CD*CD;
  unsigned short* kg = qg + (size_t)NB*NH*LPAD*HD;
  unsigned short* vt = kg + (size_t)NB*NH*LPAD*HD;

  prep_kernel<<<2048, 256, 0, stream>>>(x, wqkv, projw, xb, wb, pw);
  gemm_qkv<<<480, 512, 0, stream>>>(xb, wb, qb, vb, qg, kg, vt);
  rope_norm<<<dim3(158, 64), 256, 0, stream>>>(qg, kg, rope, smlog);
  attn_kernel<<<dim3(20, 32), 256, 0, stream>>>(qg, kg, vt, xb);
  gemm_proj<<<160, 512, 0, stream>>>(xb, pw, projb, out);
}